// Round 1
// baseline (50635.986 us; speedup 1.0000x reference)
//
#include <hip/hip_runtime.h>

// RnnGenerator: C=2048, 4-layer ReLU RNN, 512 autoregressive steps.
// Key fact: _unit_norm is over a size-1 axis => elementwise v/(|v|+1e-12),
// i.e. states binarize to ~{0,1}. 2048 strictly serial GEMV stages.
// Design: persistent kernel, 256 WGs x 512 thr (1/CU), hand-rolled grid
// barrier (monotonic counter, agent-scope atomics), fp32 everywhere
// (bf16 would flip signs of near-zero pre-activations -> chaotic divergence).

#define C        2048
#define NB       256
#define NT       512      // 8 waves per WG, 1 output row per wave per stage
#define STEPS    512
#define NLAYERS  4

// ws layout (in floats)
#define WS_CNT   0                 // barrier counter (int), own 128B line
#define WS_INP   32                // inp_buf[2][C]
#define WS_HID   (32 + 2*C)        // hid_buf[2][4][C]
#define WS_HLAY  (32 + 10*C)       // hlay[3][C]  (raw h of layers 0..2)

__device__ __forceinline__ float wred(float v) {
#pragma unroll
  for (int off = 32; off > 0; off >>= 1) v += __shfl_down(v, off, 64);
  return v;
}

// Monotonic-epoch grid barrier. cnt must be 0 at kernel start (init kernel).
__device__ __forceinline__ void gbar(int* cnt, int target) {
  __syncthreads();                      // all WG stores issued (vmcnt drained)
  if (threadIdx.x == 0) {
    __threadfence();                    // device-scope release (L2 writeback)
    __hip_atomic_fetch_add(cnt, 1, __ATOMIC_RELEASE, __HIP_MEMORY_SCOPE_AGENT);
    while (__hip_atomic_load(cnt, __ATOMIC_RELAXED, __HIP_MEMORY_SCOPE_AGENT) < target)
      __builtin_amdgcn_s_sleep(1);
    __threadfence();                    // device-scope acquire (L1/L2 inv)
  }
  __syncthreads();
}

__global__ void init_kernel(const float* __restrict__ x, float* __restrict__ ws) {
  int i = blockIdx.x * blockDim.x + threadIdx.x;
  if (i == 0) ((int*)ws)[WS_CNT] = 0;
  if (i < C) {
    ws[WS_INP + i] = 0.f;                    // inp parity 0 = zeros
    ws[WS_HID + 0 * C + i] = x[i];           // hid parity 0, layer 0 = x
    ws[WS_HID + 1 * C + i] = 0.f;
    ws[WS_HID + 2 * C + i] = 0.f;
    ws[WS_HID + 3 * C + i] = 0.f;
  }
}

__global__ __launch_bounds__(NT) void rnn_persist(
    const float* __restrict__ x,
    const float* __restrict__ lp_w,  const float* __restrict__ lp_b,
    const float* __restrict__ lp_wout, const float* __restrict__ lp_bout,
    const float* __restrict__ w_ih,  const float* __restrict__ b_ih,
    const float* __restrict__ w_hh,  const float* __restrict__ b_hh,
    float* __restrict__ out, float* __restrict__ ws)
{
  __shared__ __align__(16) float sh_a[C];
  __shared__ __align__(16) float sh_b[C];
  int* cnt = (int*)ws;          // WS_CNT == 0
  float* inp_buf = ws + WS_INP;
  float* hid_buf = ws + WS_HID;
  float* hlay    = ws + WS_HLAY;

  const int tid  = threadIdx.x;
  const int lane = tid & 63;
  const int wid  = tid >> 6;
  const int j    = blockIdx.x * 8 + wid;   // output row owned by this wave
  int ep = 0;

  float4* shA4 = (float4*)sh_a;
  float4* shB4 = (float4*)sh_b;

  // ---------------- LengthProducer: 3 x (Linear + LeakyReLU(0.2)) ----------
  for (int s = 0; s < 3; ++s) {
    const float* vin = (s == 0) ? x : (hlay + (size_t)(s - 1) * C);
    shA4[tid] = ((const float4*)vin)[tid];
    __syncthreads();
    const float4* W4 = (const float4*)(lp_w + ((size_t)s * C + j) * C);
    float a0 = 0, a1 = 0, a2 = 0, a3 = 0;
#pragma unroll
    for (int it = 0; it < 8; ++it) {
      int idx = it * 64 + lane;
      float4 w = W4[idx]; float4 h = shA4[idx];
      a0 = fmaf(w.x, h.x, a0); a1 = fmaf(w.y, h.y, a1);
      a2 = fmaf(w.z, h.z, a2); a3 = fmaf(w.w, h.w, a3);
    }
    float acc = wred((a0 + a1) + (a2 + a3));
    if (lane == 0) {
      float v = acc + lp_b[s * C + j];
      hlay[(size_t)s * C + j] = (v >= 0.f) ? v : 0.2f * v;
    }
    gbar(cnt, (++ep) * NB);
  }

  // final LP row: l = clamp(|wout . y + bout|, 0, 0.9999) -> out[STEPS*C]
  if (blockIdx.x == 0 && wid == 0) {
    const float* y = hlay + 2 * C;
    float p = 0.f;
    for (int k = lane; k < C; k += 64) p = fmaf(lp_wout[k], y[k], p);
    p = wred(p);
    if (lane == 0) {
      float l = fabsf(p + lp_bout[0]);
      out[(size_t)STEPS * C] = fminf(l, 0.9999f);
    }
  }

  // ---------------- 512 steps x 4 layers, serial stages --------------------
  for (int t = 0; t < STEPS; ++t) {
    const int p = t & 1;
    for (int l = 0; l < NLAYERS; ++l) {
      const float* hin_g = (l == 0) ? (inp_buf + (size_t)p * C)
                                    : (hlay + (size_t)(l - 1) * C);
      const float* hid_g = hid_buf + (size_t)(p * 4 + l) * C;
      shA4[tid] = ((const float4*)hin_g)[tid];
      shB4[tid] = ((const float4*)hid_g)[tid];
      __syncthreads();

      const float4* Wi4 = (const float4*)(w_ih + ((size_t)l * C + j) * C);
      const float4* Wh4 = (const float4*)(w_hh + ((size_t)l * C + j) * C);
      float a0 = 0, a1 = 0, a2 = 0, a3 = 0;
      float b0 = 0, b1 = 0, b2 = 0, b3 = 0;
#pragma unroll
      for (int it = 0; it < 8; ++it) {
        int idx = it * 64 + lane;
        float4 wi = Wi4[idx]; float4 ha = shA4[idx];
        a0 = fmaf(wi.x, ha.x, a0); a1 = fmaf(wi.y, ha.y, a1);
        a2 = fmaf(wi.z, ha.z, a2); a3 = fmaf(wi.w, ha.w, a3);
        float4 wh = Wh4[idx]; float4 hb = shB4[idx];
        b0 = fmaf(wh.x, hb.x, b0); b1 = fmaf(wh.y, hb.y, b1);
        b2 = fmaf(wh.z, hb.z, b2); b3 = fmaf(wh.w, hb.w, b3);
      }
      float acc = wred(((a0 + a1) + (a2 + a3)) + ((b0 + b1) + (b2 + b3)));

      if (lane == 0) {
        float pre = acc + b_ih[l * C + j] + b_hh[l * C + j];
        float h   = fmaxf(pre, 0.f);
        float bin = h / (h + 1e-12f);            // unit_norm over size-1 axis
        if (l < 3) hlay[(size_t)l * C + j] = h;  // raw h feeds next layer
        hid_buf[(size_t)((p ^ 1) * 4 + l) * C + j] = bin;
        if (l == 3) {
          inp_buf[(size_t)(p ^ 1) * C + j] = bin;
          out[(size_t)t * C + j] = bin;          // emitted seq row
        }
      }
      gbar(cnt, (++ep) * NB);
    }
  }
}

extern "C" void kernel_launch(void* const* d_in, const int* in_sizes, int n_in,
                              void* d_out, int out_size, void* d_ws, size_t ws_size,
                              hipStream_t stream) {
  const float* x       = (const float*)d_in[0];
  const float* lp_w    = (const float*)d_in[1];
  const float* lp_b    = (const float*)d_in[2];
  const float* lp_wout = (const float*)d_in[3];
  const float* lp_bout = (const float*)d_in[4];
  const float* w_ih    = (const float*)d_in[5];
  const float* b_ih    = (const float*)d_in[6];
  const float* w_hh    = (const float*)d_in[7];
  const float* b_hh    = (const float*)d_in[8];
  float* out = (float*)d_out;
  float* ws  = (float*)d_ws;

  hipLaunchKernelGGL(init_kernel, dim3(8), dim3(256), 0, stream, x, ws);
  hipLaunchKernelGGL(rnn_persist, dim3(NB), dim3(NT), 0, stream,
                     x, lp_w, lp_b, lp_wout, lp_bout,
                     w_ih, b_ih, w_hh, b_hh, out, ws);
}

// Round 3
// 23080.235 us; speedup vs baseline: 2.1939x; 2.1939x over previous
//
#include <hip/hip_runtime.h>

// RnnGenerator: C=2048, 4-layer ReLU RNN, 512 autoregressive steps (2048
// strictly serial GEMV stages) + 3-layer MLP LengthProducer.
// Round-3 design (round-2 + fence spelling fix):
//  - 256 WGs x 512 thr (8 waves), 1 WG/CU, wave w owns unit j = bid*8+w.
//  - Weight residency: layers 0-2 rows in VGPRs (192 regs float4/wave),
//    layer 3 rows in LDS (128 KB/CU). One-time 134 MB prime; per-stage
//    global traffic = 16 KB h-exchange only.
//  - Grid barrier: per-WG epoch flag array (single-writer, no RMW).
//    Arrival: vmcnt-drain + relaxed agent store. Wave0 polls 256 flags
//    (4 coalesced loads/lane across 8 lines) with s_sleep backoff, then
//    agent acquire fence via __builtin_amdgcn_fence (buffer_inv).
//    Regs/LDS-resident weights are immune to the invalidate.
//  - h produced via agent-scope (write-through) stores; consumed via plain
//    coalesced float4 loads after the acquire fence.
// fp32 everywhere: states binarize to exactly {0,1} (h/(h+1e-12) with
// h+1e-12==h in fp32); bf16 weights would flip near-zero pre-act signs.

#define C        2048
#define NB       256
#define NT       512
#define STEPS    512

// ws layout (float indices)
#define WS_FLAGS 0                  // 256 ints, 1 KB
#define WS_INP   256                // inp[2][C]
#define WS_HIDB  (256 + 2*C)        // hidb[2][4][C]
#define WS_HRAW  (256 + 10*C)       // hraw[3][C]
#define WS_LP    (256 + 13*C)       // lp_hlay[3][C]

__device__ __forceinline__ float wred(float v) {
#pragma unroll
  for (int off = 32; off > 0; off >>= 1) v += __shfl_down(v, off, 64);
  return v;
}

__device__ __forceinline__ void st_agent(float* p, float v) {
  __hip_atomic_store(p, v, __ATOMIC_RELAXED, __HIP_MEMORY_SCOPE_AGENT);
}

// Flag-array grid barrier, monotonic epochs. flags[] zeroed by init kernel.
__device__ __forceinline__ void gbar(int* flags, int ep) {
  asm volatile("s_waitcnt vmcnt(0)" ::: "memory");  // own stores at coherence pt
  __syncthreads();                                   // all waves drained
  if (threadIdx.x < 64) {
    if (threadIdx.x == 0)
      __hip_atomic_store(&flags[blockIdx.x], ep, __ATOMIC_RELAXED,
                         __HIP_MEMORY_SCOPE_AGENT);
    const int base = threadIdx.x;
    for (;;) {
      int f0 = __hip_atomic_load(&flags[base],       __ATOMIC_RELAXED, __HIP_MEMORY_SCOPE_AGENT);
      int f1 = __hip_atomic_load(&flags[base + 64],  __ATOMIC_RELAXED, __HIP_MEMORY_SCOPE_AGENT);
      int f2 = __hip_atomic_load(&flags[base + 128], __ATOMIC_RELAXED, __HIP_MEMORY_SCOPE_AGENT);
      int f3 = __hip_atomic_load(&flags[base + 192], __ATOMIC_RELAXED, __HIP_MEMORY_SCOPE_AGENT);
      bool ok = (f0 >= ep) && (f1 >= ep) && (f2 >= ep) && (f3 >= ep);
      if (__all(ok)) break;
      __builtin_amdgcn_s_sleep(16);
    }
    __builtin_amdgcn_fence(__ATOMIC_ACQUIRE, "agent");  // L1 inv (buffer_inv)
  }
  __syncthreads();
}

__global__ void init_kernel(const float* __restrict__ x, float* __restrict__ ws) {
  int i = blockIdx.x * blockDim.x + threadIdx.x;
  if (i < 256) ((int*)ws)[WS_FLAGS + i] = 0;
  if (i < C) {
    ws[WS_INP + i] = 0.f;                      // inp parity 0 = zeros
    ws[WS_HIDB + 0 * C + i] = x[i];            // hid parity 0, layer 0 = x
    ws[WS_HIDB + 1 * C + i] = 0.f;
    ws[WS_HIDB + 2 * C + i] = 0.f;
    ws[WS_HIDB + 3 * C + i] = 0.f;
  }
}

__global__ __launch_bounds__(NT, 2) void rnn_persist(
    const float* __restrict__ x,
    const float* __restrict__ lp_w,  const float* __restrict__ lp_b,
    const float* __restrict__ lp_wout, const float* __restrict__ lp_bout,
    const float* __restrict__ w_ih,  const float* __restrict__ b_ih,
    const float* __restrict__ w_hh,  const float* __restrict__ b_hh,
    float* __restrict__ out, float* __restrict__ ws)
{
  extern __shared__ float4 w3[];   // [8 waves][2 mats][512 float4] = 128 KB
  int*   flags   = (int*)ws + WS_FLAGS;
  float* inp_buf = ws + WS_INP;
  float* hidb    = ws + WS_HIDB;
  float* hraw    = ws + WS_HRAW;
  float* lp_hlay = ws + WS_LP;

  const int tid  = threadIdx.x;
  const int lane = tid & 63;
  const int wid  = tid >> 6;
  const int j    = blockIdx.x * 8 + wid;     // unit owned by this wave
  int ep = 0;

  // ---------------- prime: layers 0-2 rows -> regs, layer 3 -> LDS --------
  const float4* WI = (const float4*)w_ih;    // row (l,j) at (l*C+j)*512
  const float4* WH = (const float4*)w_hh;
  float4 wir[3][8], whr[3][8];
#pragma unroll
  for (int l = 0; l < 3; ++l) {
    const size_t bi = (size_t)(l * C + j) * 512;
#pragma unroll
    for (int r = 0; r < 8; ++r) {
      wir[l][r] = WI[bi + r * 64 + lane];
      whr[l][r] = WH[bi + r * 64 + lane];
    }
  }
  {
    const size_t b3 = (size_t)(3 * C + j) * 512;
#pragma unroll
    for (int r = 0; r < 8; ++r) {
      w3[(wid * 2 + 0) * 512 + r * 64 + lane] = WI[b3 + r * 64 + lane];
      w3[(wid * 2 + 1) * 512 + r * 64 + lane] = WH[b3 + r * 64 + lane];
    }
  }
  float bias[4];
#pragma unroll
  for (int l = 0; l < 4; ++l) bias[l] = b_ih[l * C + j] + b_hh[l * C + j];
  __syncthreads();

  // ---------------- LengthProducer: 3 x (Linear + LeakyReLU(0.2)) ---------
  for (int s = 0; s < 3; ++s) {
    const float4* vin4 = (const float4*)((s == 0) ? x : (lp_hlay + (size_t)(s - 1) * C));
    const float4* Wr   = (const float4*)(lp_w + ((size_t)s * C + j) * C);
    float a0 = 0, a1 = 0, a2 = 0, a3 = 0;
#pragma unroll
    for (int r = 0; r < 8; ++r) {
      float4 w = Wr[r * 64 + lane]; float4 h = vin4[r * 64 + lane];
      a0 = fmaf(w.x, h.x, a0); a1 = fmaf(w.y, h.y, a1);
      a2 = fmaf(w.z, h.z, a2); a3 = fmaf(w.w, h.w, a3);
    }
    float acc = wred((a0 + a1) + (a2 + a3));
    if (lane == 0) {
      float v = acc + lp_b[s * C + j];
      st_agent(&lp_hlay[(size_t)s * C + j], (v >= 0.f) ? v : 0.2f * v);
    }
    gbar(flags, ++ep);
  }

  // final LP row: l = clamp(|wout . y + bout|, 0, 0.9999) -> out[STEPS*C]
  if (blockIdx.x == 0 && wid == 0) {
    const float* y = lp_hlay + 2 * C;
    float p = 0.f;
    for (int k = lane; k < C; k += 64) p = fmaf(lp_wout[k], y[k], p);
    p = wred(p);
    if (lane == 0) {
      float l = fabsf(p + lp_bout[0]);
      out[(size_t)STEPS * C] = fminf(l, 0.9999f);
    }
  }

  // ---------------- 512 steps x 4 layers ----------------------------------
  for (int t = 0; t < STEPS; ++t) {
    const int p = t & 1;

    // layers 0..2: weights in registers
#pragma unroll
    for (int l = 0; l < 3; ++l) {
      const float4* vin4 = (const float4*)((l == 0) ? (inp_buf + (size_t)p * C)
                                                    : (hraw + (size_t)(l - 1) * C));
      const float4* hid4 = (const float4*)(hidb + (size_t)(p * 4 + l) * C);
      float a0 = 0, a1 = 0, a2 = 0, a3 = 0;
#pragma unroll
      for (int r = 0; r < 8; ++r) {
        float4 h = vin4[r * 64 + lane]; float4 w = wir[l][r];
        a0 = fmaf(w.x, h.x, a0); a1 = fmaf(w.y, h.y, a1);
        a2 = fmaf(w.z, h.z, a2); a3 = fmaf(w.w, h.w, a3);
        float4 g = hid4[r * 64 + lane]; float4 v = whr[l][r];
        a0 = fmaf(v.x, g.x, a0); a1 = fmaf(v.y, g.y, a1);
        a2 = fmaf(v.z, g.z, a2); a3 = fmaf(v.w, g.w, a3);
      }
      float acc = wred((a0 + a1) + (a2 + a3));
      if (lane == 0) {
        float pre = acc + bias[l];
        float h   = fmaxf(pre, 0.f);
        float bin = h / (h + 1e-12f);
        st_agent(&hraw[(size_t)l * C + j], h);
        st_agent(&hidb[(size_t)((p ^ 1) * 4 + l) * C + j], bin);
      }
      gbar(flags, ++ep);
    }

    // layer 3: weights in LDS
    {
      const float4* vin4 = (const float4*)(hraw + (size_t)2 * C);
      const float4* hid4 = (const float4*)(hidb + (size_t)(p * 4 + 3) * C);
      float a0 = 0, a1 = 0, a2 = 0, a3 = 0;
#pragma unroll
      for (int r = 0; r < 8; ++r) {
        float4 h = vin4[r * 64 + lane]; float4 w = w3[(wid * 2 + 0) * 512 + r * 64 + lane];
        a0 = fmaf(w.x, h.x, a0); a1 = fmaf(w.y, h.y, a1);
        a2 = fmaf(w.z, h.z, a2); a3 = fmaf(w.w, h.w, a3);
        float4 g = hid4[r * 64 + lane]; float4 v = w3[(wid * 2 + 1) * 512 + r * 64 + lane];
        a0 = fmaf(v.x, g.x, a0); a1 = fmaf(v.y, g.y, a1);
        a2 = fmaf(v.z, g.z, a2); a3 = fmaf(v.w, g.w, a3);
      }
      float acc = wred((a0 + a1) + (a2 + a3));
      if (lane == 0) {
        float pre = acc + bias[3];
        float h   = fmaxf(pre, 0.f);
        float bin = h / (h + 1e-12f);
        st_agent(&hidb[(size_t)((p ^ 1) * 4 + 3) * C + j], bin);
        st_agent(&inp_buf[(size_t)(p ^ 1) * C + j], bin);
        out[(size_t)t * C + j] = bin;
      }
      gbar(flags, ++ep);
    }
  }
}

extern "C" void kernel_launch(void* const* d_in, const int* in_sizes, int n_in,
                              void* d_out, int out_size, void* d_ws, size_t ws_size,
                              hipStream_t stream) {
  const float* x       = (const float*)d_in[0];
  const float* lp_w    = (const float*)d_in[1];
  const float* lp_b    = (const float*)d_in[2];
  const float* lp_wout = (const float*)d_in[3];
  const float* lp_bout = (const float*)d_in[4];
  const float* w_ih    = (const float*)d_in[5];
  const float* b_ih    = (const float*)d_in[6];
  const float* w_hh    = (const float*)d_in[7];
  const float* b_hh    = (const float*)d_in[8];
  float* out = (float*)d_out;
  float* ws  = (float*)d_ws;

  hipLaunchKernelGGL(init_kernel, dim3(8), dim3(256), 0, stream, x, ws);
  hipLaunchKernelGGL(rnn_persist, dim3(NB), dim3(NT),
                     8 * 2 * 512 * sizeof(float4) /* 128 KB LDS */, stream,
                     x, lp_w, lp_b, lp_wout, lp_bout,
                     w_ih, b_ih, w_hh, b_hh, out, ws);
}

// Round 4
// 13612.199 us; speedup vs baseline: 3.7199x; 1.6956x over previous
//
#include <hip/hip_runtime.h>

// RnnGenerator: C=2048, 4-layer ReLU RNN, 512 autoregressive steps = 2048
// strictly serial GEMV stages (input recurrence inp(t)=bin(h3(t-1)) forbids
// layer pipelining) + 3-layer MLP LengthProducer.
// Round-4: BARRIER-FREE EPOCH-TAGGED DATAFLOW.
//  - Every exchanged element is 8B {f32 value | i32 tag}; producer = one
//    relaxed agent-scope 8B store; consumer polls tagged elements straight
//    into LDS. No fences, no vmcnt drains, no flags, no buffer_inv.
//  - stage(t,l) id = 4t+l, publishes tag 4t+l+1. Consumer (t,l) expects:
//    A: l==0 -> inp[t&1] tag 4t ; l>0 -> hraw[l-1] tag 4t+l.
//    B: hidb[t&1][l] tag 4t+l-3. Init seeds t=0 tags (0 and l-3).
//    Buffer reuse is >=4 stages apart; the all-to-all dependency chain makes
//    overwrite-before-read impossible.
//  - Weight residency as round 3: layers 0-2 rows in VGPRs, layer 3 in LDS
//    (128 KB dyn) + 16 KB static LDS for staged vectors. 1 WG/CU.
// fp32 everywhere: states binarize to exactly {0,1}; bf16 would flip
// near-zero pre-activation signs and the trajectory is chaotic to that.

#define C      2048
#define NB     256
#define NT     512
#define STEPS  512

typedef unsigned long long u64;

// ws layout in u64 units
#define U_INP   0            // inp[2][C]
#define U_HIDB  (2*C)        // hidb[2][4][C]
#define U_HRAW  (10*C)       // hraw[3][C]
#define U_LP    (13*C)       // lp[3][C]     (total 16*C u64 = 256 KB)

__device__ __forceinline__ float wred(float v) {
#pragma unroll
  for (int off = 32; off > 0; off >>= 1) v += __shfl_down(v, off, 64);
  return v;
}

__device__ __forceinline__ u64 pack(float val, int tag) {
  return ((u64)(unsigned)tag << 32) | (u64)__float_as_uint(val);
}
__device__ __forceinline__ void pub(u64* p, float val, int tag) {
  __hip_atomic_store(p, pack(val, tag), __ATOMIC_RELAXED, __HIP_MEMORY_SCOPE_AGENT);
}
__device__ __forceinline__ u64 peek(u64* p) {
  return __hip_atomic_load(p, __ATOMIC_RELAXED, __HIP_MEMORY_SCOPE_AGENT);
}

// Poll two tagged vectors into LDS. Each thread owns elements r*NT+tid.
__device__ __forceinline__ void poll2(u64* A, int tagA, u64* B, int tagB,
                                      float* sa, float* sb, int tid) {
  unsigned pend = 0xFFu;
  for (;;) {
#pragma unroll
    for (int r = 0; r < 4; ++r) {
      const int e = r * NT + tid;
      if (pend & (1u << r)) {
        u64 v = peek(&A[e]);
        if ((int)(v >> 32) == tagA) { sa[e] = __uint_as_float((unsigned)v); pend &= ~(1u << r); }
      }
      if (pend & (1u << (r + 4))) {
        u64 v = peek(&B[e]);
        if ((int)(v >> 32) == tagB) { sb[e] = __uint_as_float((unsigned)v); pend &= ~(1u << (r + 4)); }
      }
    }
    if (!pend) break;
    __builtin_amdgcn_s_sleep(1);
  }
}

__device__ __forceinline__ void poll1(u64* A, int tagA, float* sa, int tid) {
  unsigned pend = 0xFu;
  for (;;) {
#pragma unroll
    for (int r = 0; r < 4; ++r) {
      const int e = r * NT + tid;
      if (pend & (1u << r)) {
        u64 v = peek(&A[e]);
        if ((int)(v >> 32) == tagA) { sa[e] = __uint_as_float((unsigned)v); pend &= ~(1u << r); }
      }
    }
    if (!pend) break;
    __builtin_amdgcn_s_sleep(1);
  }
}

__global__ void init_kernel(const float* __restrict__ x, u64* __restrict__ ws) {
  int i = blockIdx.x * blockDim.x + threadIdx.x;
  if (i < C) {
    ws[U_INP + i]          = pack(0.f, 0);    // inp(t=0) expects tag 0
    ws[U_HIDB + 0 * C + i] = pack(x[i], -3);  // hid_l(t=-1): tag l-3
    ws[U_HIDB + 1 * C + i] = pack(0.f, -2);
    ws[U_HIDB + 2 * C + i] = pack(0.f, -1);
    ws[U_HIDB + 3 * C + i] = pack(0.f, 0);
  }
}

__global__ __launch_bounds__(NT, 2) void rnn_persist(
    const float* __restrict__ x,
    const float* __restrict__ lp_w,  const float* __restrict__ lp_b,
    const float* __restrict__ lp_wout, const float* __restrict__ lp_bout,
    const float* __restrict__ w_ih,  const float* __restrict__ b_ih,
    const float* __restrict__ w_hh,  const float* __restrict__ b_hh,
    float* __restrict__ out, u64* __restrict__ ws)
{
  extern __shared__ float4 w3[];            // 8 waves x 2 mats x 512 f4 = 128 KB
  __shared__ __align__(16) float sh_a[C];   // 8 KB staged input vector
  __shared__ __align__(16) float sh_b[C];   // 8 KB staged hidden vector

  u64* inp  = ws + U_INP;
  u64* hidb = ws + U_HIDB;
  u64* hraw = ws + U_HRAW;
  u64* lp   = ws + U_LP;

  const int tid  = threadIdx.x;
  const int lane = tid & 63;
  const int wid  = tid >> 6;
  const int j    = blockIdx.x * 8 + wid;    // unit owned by this wave

  // ---------------- prime: layers 0-2 rows -> regs, layer 3 -> LDS --------
  const float4* WI = (const float4*)w_ih;
  const float4* WH = (const float4*)w_hh;
  float4 wir[3][8], whr[3][8];
#pragma unroll
  for (int l = 0; l < 3; ++l) {
    const size_t bi = (size_t)(l * C + j) * 512;
#pragma unroll
    for (int r = 0; r < 8; ++r) {
      wir[l][r] = WI[bi + r * 64 + lane];
      whr[l][r] = WH[bi + r * 64 + lane];
    }
  }
  {
    const size_t b3 = (size_t)(3 * C + j) * 512;
#pragma unroll
    for (int r = 0; r < 8; ++r) {
      w3[(wid * 2 + 0) * 512 + r * 64 + lane] = WI[b3 + r * 64 + lane];
      w3[(wid * 2 + 1) * 512 + r * 64 + lane] = WH[b3 + r * 64 + lane];
    }
  }
  float bias[4];
#pragma unroll
  for (int l = 0; l < 4; ++l) bias[l] = b_ih[l * C + j] + b_hh[l * C + j];
  __syncthreads();

  // ---------------- LengthProducer (dataflow, overlaps nothing serial) ----
  for (int s = 0; s < 3; ++s) {
    if (s == 0) ((float4*)sh_a)[tid] = ((const float4*)x)[tid];
    else        poll1(lp + (size_t)(s - 1) * C, s, sh_a, tid);
    __syncthreads();
    const float4* Wr = (const float4*)(lp_w + ((size_t)s * C + j) * C);
    const float4* sa4 = (const float4*)sh_a;
    float a0 = 0, a1 = 0, a2 = 0, a3 = 0;
#pragma unroll
    for (int r = 0; r < 8; ++r) {
      float4 w = Wr[r * 64 + lane]; float4 h = sa4[r * 64 + lane];
      a0 = fmaf(w.x, h.x, a0); a1 = fmaf(w.y, h.y, a1);
      a2 = fmaf(w.z, h.z, a2); a3 = fmaf(w.w, h.w, a3);
    }
    float acc = wred((a0 + a1) + (a2 + a3));
    if (lane == 0) {
      float v = acc + lp_b[s * C + j];
      pub(&lp[(size_t)s * C + j], (v >= 0.f) ? v : 0.2f * v, s + 1);
    }
    __syncthreads();   // sh_a reuse protection
  }

  // LP head: block 0 wave 0 polls lp[2] (tag 3) and emits scalar l.
  if (blockIdx.x == 0 && wid == 0) {
    float p = 0.f;
#pragma unroll 4
    for (int r = 0; r < 32; ++r) {
      const int e = r * 64 + lane;
      u64 v;
      do { v = peek(&lp[2 * C + e]); } while ((int)(v >> 32) != 3);
      p = fmaf(lp_wout[e], __uint_as_float((unsigned)v), p);
    }
    p = wred(p);
    if (lane == 0) {
      float l = fabsf(p + lp_bout[0]);
      out[(size_t)STEPS * C] = fminf(l, 0.9999f);
    }
  }

  // ---------------- 512 steps x 4 layers, pure dataflow -------------------
  for (int t = 0; t < STEPS; ++t) {
    const int p = t & 1;
#pragma unroll
    for (int l = 0; l < 4; ++l) {
      u64* A    = (l == 0) ? (inp + (size_t)p * C) : (hraw + (size_t)(l - 1) * C);
      int  tagA = (l == 0) ? (4 * t) : (4 * t + l);
      u64* B    = hidb + (size_t)(p * 4 + l) * C;
      int  tagB = 4 * t + l - 3;
      poll2(A, tagA, B, tagB, sh_a, sh_b, tid);
      __syncthreads();

      const float4* sa4 = (const float4*)sh_a;
      const float4* sb4 = (const float4*)sh_b;
      float a0 = 0, a1 = 0, a2 = 0, a3 = 0;
      if (l < 3) {
#pragma unroll
        for (int r = 0; r < 8; ++r) {
          float4 h = sa4[r * 64 + lane]; float4 w = wir[l][r];
          a0 = fmaf(w.x, h.x, a0); a1 = fmaf(w.y, h.y, a1);
          a2 = fmaf(w.z, h.z, a2); a3 = fmaf(w.w, h.w, a3);
          float4 g = sb4[r * 64 + lane]; float4 v = whr[l][r];
          a0 = fmaf(v.x, g.x, a0); a1 = fmaf(v.y, g.y, a1);
          a2 = fmaf(v.z, g.z, a2); a3 = fmaf(v.w, g.w, a3);
        }
      } else {
#pragma unroll
        for (int r = 0; r < 8; ++r) {
          float4 h = sa4[r * 64 + lane]; float4 w = w3[(wid * 2 + 0) * 512 + r * 64 + lane];
          a0 = fmaf(w.x, h.x, a0); a1 = fmaf(w.y, h.y, a1);
          a2 = fmaf(w.z, h.z, a2); a3 = fmaf(w.w, h.w, a3);
          float4 g = sb4[r * 64 + lane]; float4 v = w3[(wid * 2 + 1) * 512 + r * 64 + lane];
          a0 = fmaf(v.x, g.x, a0); a1 = fmaf(v.y, g.y, a1);
          a2 = fmaf(v.z, g.z, a2); a3 = fmaf(v.w, g.w, a3);
        }
      }
      float acc = wred((a0 + a1) + (a2 + a3));

      if (lane == 0) {
        float pre = acc + bias[l];
        float h   = fmaxf(pre, 0.f);
        float bin = h / (h + 1e-12f);
        const int tg = 4 * t + l + 1;
        if (l < 3) {
          pub(&hraw[(size_t)l * C + j], h, tg);
          pub(&hidb[(size_t)((p ^ 1) * 4 + l) * C + j], bin, tg);
        } else {
          pub(&hidb[(size_t)((p ^ 1) * 4 + 3) * C + j], bin, tg);
          pub(&inp[(size_t)(p ^ 1) * C + j], bin, tg);
          out[(size_t)t * C + j] = bin;
        }
      }
      __syncthreads();   // sh_a/sh_b reuse protection before next poll
    }
  }
}

extern "C" void kernel_launch(void* const* d_in, const int* in_sizes, int n_in,
                              void* d_out, int out_size, void* d_ws, size_t ws_size,
                              hipStream_t stream) {
  const float* x       = (const float*)d_in[0];
  const float* lp_w    = (const float*)d_in[1];
  const float* lp_b    = (const float*)d_in[2];
  const float* lp_wout = (const float*)d_in[3];
  const float* lp_bout = (const float*)d_in[4];
  const float* w_ih    = (const float*)d_in[5];
  const float* b_ih    = (const float*)d_in[6];
  const float* w_hh    = (const float*)d_in[7];
  const float* b_hh    = (const float*)d_in[8];
  float* out = (float*)d_out;
  u64*   ws  = (u64*)d_ws;

  hipLaunchKernelGGL(init_kernel, dim3(8), dim3(256), 0, stream, x, ws);
  hipLaunchKernelGGL(rnn_persist, dim3(NB), dim3(NT),
                     8 * 2 * 512 * sizeof(float4) /* 128 KB dyn LDS */, stream,
                     x, lp_w, lp_b, lp_wout, lp_bout,
                     w_ih, b_ih, w_hh, b_hh, out, ws);
}

// Round 5
// 12119.074 us; speedup vs baseline: 4.1782x; 1.1232x over previous
//
#include <hip/hip_runtime.h>

// RnnGenerator: C=2048, 4-layer ReLU RNN, 512 autoregressive steps = 2048
// strictly serial GEMV stages + 3-layer MLP LengthProducer.
// Round-5: round-4 epoch-tagged dataflow, with BATCHED poll loads.
//  - Round-4 bug: each polled 8B atomic load was tag-tested immediately ->
//    compiler waits per load -> 8 coherence-point misses SERIALIZE per round
//    (~6.65us/stage). Fix: issue all 8 loads back-to-back into regs, one
//    vmcnt drain, check all tags at once -> round ~= 1 miss latency.
//  - Thread owns 4 contiguous elements/vector; LDS staging via one
//    ds_write_b128 per vector AFTER loop exit (regs already hold values).
//  - Producer publishes critical-chain value first (hraw / inp before hidb).
//  - Weight residency: layers 0-2 rows in VGPRs, layer 3 in LDS (128 KB dyn),
//    16 KB static LDS for staged vectors. 256 WGs x 512 thr, 1 WG/CU.
// fp32 everywhere: states binarize to exactly {0,1}; bf16 would flip
// near-zero pre-activation signs (trajectory is chaotic to that).

#define C      2048
#define NB     256
#define NT     512
#define STEPS  512

typedef unsigned long long u64;

// ws layout in u64 units
#define U_INP   0            // inp[2][C]
#define U_HIDB  (2*C)        // hidb[2][4][C]
#define U_HRAW  (10*C)       // hraw[3][C]
#define U_LP    (13*C)       // lp[3][C]

__device__ __forceinline__ float wred(float v) {
#pragma unroll
  for (int off = 32; off > 0; off >>= 1) v += __shfl_down(v, off, 64);
  return v;
}

__device__ __forceinline__ u64 pack(float val, int tag) {
  return ((u64)(unsigned)tag << 32) | (u64)__float_as_uint(val);
}
__device__ __forceinline__ void pub(u64* p, float val, int tag) {
  __hip_atomic_store(p, pack(val, tag), __ATOMIC_RELAXED, __HIP_MEMORY_SCOPE_AGENT);
}
__device__ __forceinline__ u64 peek(u64* p) {
  return __hip_atomic_load(p, __ATOMIC_RELAXED, __HIP_MEMORY_SCOPE_AGENT);
}
__device__ __forceinline__ float val_of(u64 v) { return __uint_as_float((unsigned)v); }
__device__ __forceinline__ int   tag_of(u64 v) { return (int)(v >> 32); }

// Batched poll of two tagged vectors into LDS. Thread owns A/B[4*tid..4*tid+3].
__device__ __forceinline__ void poll2(u64* __restrict__ A, int tagA,
                                      u64* __restrict__ B, int tagB,
                                      float* __restrict__ sa, float* __restrict__ sb,
                                      int tid) {
  u64* a = A + 4 * tid;
  u64* b = B + 4 * tid;
  u64 va0, va1, va2, va3, vb0, vb1, vb2, vb3;
  for (;;) {
    va0 = peek(a + 0); va1 = peek(a + 1); va2 = peek(a + 2); va3 = peek(a + 3);
    vb0 = peek(b + 0); vb1 = peek(b + 1); vb2 = peek(b + 2); vb3 = peek(b + 3);
    bool ok = (tag_of(va0) == tagA) & (tag_of(va1) == tagA)
            & (tag_of(va2) == tagA) & (tag_of(va3) == tagA)
            & (tag_of(vb0) == tagB) & (tag_of(vb1) == tagB)
            & (tag_of(vb2) == tagB) & (tag_of(vb3) == tagB);
    if (ok) break;
    __builtin_amdgcn_s_sleep(2);
  }
  float4 fa = { val_of(va0), val_of(va1), val_of(va2), val_of(va3) };
  float4 fb = { val_of(vb0), val_of(vb1), val_of(vb2), val_of(vb3) };
  ((float4*)sa)[tid] = fa;
  ((float4*)sb)[tid] = fb;
}

__device__ __forceinline__ void poll1(u64* __restrict__ A, int tagA,
                                      float* __restrict__ sa, int tid) {
  u64* a = A + 4 * tid;
  u64 va0, va1, va2, va3;
  for (;;) {
    va0 = peek(a + 0); va1 = peek(a + 1); va2 = peek(a + 2); va3 = peek(a + 3);
    bool ok = (tag_of(va0) == tagA) & (tag_of(va1) == tagA)
            & (tag_of(va2) == tagA) & (tag_of(va3) == tagA);
    if (ok) break;
    __builtin_amdgcn_s_sleep(2);
  }
  float4 fa = { val_of(va0), val_of(va1), val_of(va2), val_of(va3) };
  ((float4*)sa)[tid] = fa;
}

__global__ void init_kernel(const float* __restrict__ x, u64* __restrict__ ws) {
  int i = blockIdx.x * blockDim.x + threadIdx.x;
  if (i < C) {
    ws[U_INP + i]          = pack(0.f, 0);    // inp(t=0) expects tag 0
    ws[U_HIDB + 0 * C + i] = pack(x[i], -3);  // hid_l(t=-1): tag l-3
    ws[U_HIDB + 1 * C + i] = pack(0.f, -2);
    ws[U_HIDB + 2 * C + i] = pack(0.f, -1);
    ws[U_HIDB + 3 * C + i] = pack(0.f, 0);
  }
}

__global__ __launch_bounds__(NT, 2) void rnn_persist(
    const float* __restrict__ x,
    const float* __restrict__ lp_w,  const float* __restrict__ lp_b,
    const float* __restrict__ lp_wout, const float* __restrict__ lp_bout,
    const float* __restrict__ w_ih,  const float* __restrict__ b_ih,
    const float* __restrict__ w_hh,  const float* __restrict__ b_hh,
    float* __restrict__ out, u64* __restrict__ ws)
{
  extern __shared__ float4 w3[];            // 8 waves x 2 mats x 512 f4 = 128 KB
  __shared__ __align__(16) float sh_a[C];   // 8 KB staged input vector
  __shared__ __align__(16) float sh_b[C];   // 8 KB staged hidden vector

  u64* inp  = ws + U_INP;
  u64* hidb = ws + U_HIDB;
  u64* hraw = ws + U_HRAW;
  u64* lp   = ws + U_LP;

  const int tid  = threadIdx.x;
  const int lane = tid & 63;
  const int wid  = tid >> 6;
  const int j    = blockIdx.x * 8 + wid;    // unit owned by this wave

  // ---------------- prime: layers 0-2 rows -> regs, layer 3 -> LDS --------
  const float4* WI = (const float4*)w_ih;
  const float4* WH = (const float4*)w_hh;
  float4 wir[3][8], whr[3][8];
#pragma unroll
  for (int l = 0; l < 3; ++l) {
    const size_t bi = (size_t)(l * C + j) * 512;
#pragma unroll
    for (int r = 0; r < 8; ++r) {
      wir[l][r] = WI[bi + r * 64 + lane];
      whr[l][r] = WH[bi + r * 64 + lane];
    }
  }
  {
    const size_t b3 = (size_t)(3 * C + j) * 512;
#pragma unroll
    for (int r = 0; r < 8; ++r) {
      w3[(wid * 2 + 0) * 512 + r * 64 + lane] = WI[b3 + r * 64 + lane];
      w3[(wid * 2 + 1) * 512 + r * 64 + lane] = WH[b3 + r * 64 + lane];
    }
  }
  float bias[4];
#pragma unroll
  for (int l = 0; l < 4; ++l) bias[l] = b_ih[l * C + j] + b_hh[l * C + j];
  __syncthreads();

  // ---------------- LengthProducer (dataflow) -----------------------------
  for (int s = 0; s < 3; ++s) {
    if (s == 0) ((float4*)sh_a)[tid] = ((const float4*)x)[tid];
    else        poll1(lp + (size_t)(s - 1) * C, s, sh_a, tid);
    __syncthreads();
    const float4* Wr  = (const float4*)(lp_w + ((size_t)s * C + j) * C);
    const float4* sa4 = (const float4*)sh_a;
    float a0 = 0, a1 = 0, a2 = 0, a3 = 0;
#pragma unroll
    for (int r = 0; r < 8; ++r) {
      float4 w = Wr[r * 64 + lane]; float4 h = sa4[r * 64 + lane];
      a0 = fmaf(w.x, h.x, a0); a1 = fmaf(w.y, h.y, a1);
      a2 = fmaf(w.z, h.z, a2); a3 = fmaf(w.w, h.w, a3);
    }
    float acc = wred((a0 + a1) + (a2 + a3));
    if (lane == 0) {
      float v = acc + lp_b[s * C + j];
      pub(&lp[(size_t)s * C + j], (v >= 0.f) ? v : 0.2f * v, s + 1);
    }
    __syncthreads();   // sh_a reuse protection
  }

  // LP head: block 0 wave 0 polls lp[2] (tag 3), batched 8-wide.
  if (blockIdx.x == 0 && wid == 0) {
    float p = 0.f;
#pragma unroll
    for (int g = 0; g < 4; ++g) {
      u64 v[8];
      for (;;) {
        bool ok = true;
#pragma unroll
        for (int r = 0; r < 8; ++r)
          v[r] = peek(&lp[2 * C + (g * 8 + r) * 64 + lane]);
#pragma unroll
        for (int r = 0; r < 8; ++r) ok &= (tag_of(v[r]) == 3);
        if (ok) break;
        __builtin_amdgcn_s_sleep(2);
      }
#pragma unroll
      for (int r = 0; r < 8; ++r)
        p = fmaf(lp_wout[(g * 8 + r) * 64 + lane], val_of(v[r]), p);
    }
    p = wred(p);
    if (lane == 0) {
      float l = fabsf(p + lp_bout[0]);
      out[(size_t)STEPS * C] = fminf(l, 0.9999f);
    }
  }

  // ---------------- 512 steps x 4 layers, pure dataflow -------------------
  for (int t = 0; t < STEPS; ++t) {
    const int p = t & 1;
#pragma unroll
    for (int l = 0; l < 4; ++l) {
      u64* A    = (l == 0) ? (inp + (size_t)p * C) : (hraw + (size_t)(l - 1) * C);
      int  tagA = (l == 0) ? (4 * t) : (4 * t + l);
      u64* B    = hidb + (size_t)(p * 4 + l) * C;
      int  tagB = 4 * t + l - 3;
      poll2(A, tagA, B, tagB, sh_a, sh_b, tid);
      __syncthreads();

      const float4* sa4 = (const float4*)sh_a;
      const float4* sb4 = (const float4*)sh_b;
      float a0 = 0, a1 = 0, a2 = 0, a3 = 0;
      if (l < 3) {
#pragma unroll
        for (int r = 0; r < 8; ++r) {
          float4 h = sa4[r * 64 + lane]; float4 w = wir[l][r];
          a0 = fmaf(w.x, h.x, a0); a1 = fmaf(w.y, h.y, a1);
          a2 = fmaf(w.z, h.z, a2); a3 = fmaf(w.w, h.w, a3);
          float4 g = sb4[r * 64 + lane]; float4 v = whr[l][r];
          a0 = fmaf(v.x, g.x, a0); a1 = fmaf(v.y, g.y, a1);
          a2 = fmaf(v.z, g.z, a2); a3 = fmaf(v.w, g.w, a3);
        }
      } else {
#pragma unroll
        for (int r = 0; r < 8; ++r) {
          float4 h = sa4[r * 64 + lane]; float4 w = w3[(wid * 2 + 0) * 512 + r * 64 + lane];
          a0 = fmaf(w.x, h.x, a0); a1 = fmaf(w.y, h.y, a1);
          a2 = fmaf(w.z, h.z, a2); a3 = fmaf(w.w, h.w, a3);
          float4 g = sb4[r * 64 + lane]; float4 v = w3[(wid * 2 + 1) * 512 + r * 64 + lane];
          a0 = fmaf(v.x, g.x, a0); a1 = fmaf(v.y, g.y, a1);
          a2 = fmaf(v.z, g.z, a2); a3 = fmaf(v.w, g.w, a3);
        }
      }
      float acc = wred((a0 + a1) + (a2 + a3));

      if (lane == 0) {
        float pre = acc + bias[l];
        float h   = fmaxf(pre, 0.f);
        float bin = h / (h + 1e-12f);
        const int tg = 4 * t + l + 1;
        if (l < 3) {
          pub(&hraw[(size_t)l * C + j], h, tg);              // critical first
          pub(&hidb[(size_t)((p ^ 1) * 4 + l) * C + j], bin, tg);
        } else {
          pub(&inp[(size_t)(p ^ 1) * C + j], bin, tg);       // critical first
          pub(&hidb[(size_t)((p ^ 1) * 4 + 3) * C + j], bin, tg);
          out[(size_t)t * C + j] = bin;
        }
      }
      __syncthreads();   // sh_a/sh_b reuse protection before next poll
    }
  }
}

extern "C" void kernel_launch(void* const* d_in, const int* in_sizes, int n_in,
                              void* d_out, int out_size, void* d_ws, size_t ws_size,
                              hipStream_t stream) {
  const float* x       = (const float*)d_in[0];
  const float* lp_w    = (const float*)d_in[1];
  const float* lp_b    = (const float*)d_in[2];
  const float* lp_wout = (const float*)d_in[3];
  const float* lp_bout = (const float*)d_in[4];
  const float* w_ih    = (const float*)d_in[5];
  const float* b_ih    = (const float*)d_in[6];
  const float* w_hh    = (const float*)d_in[7];
  const float* b_hh    = (const float*)d_in[8];
  float* out = (float*)d_out;
  u64*   ws  = (u64*)d_ws;

  hipLaunchKernelGGL(init_kernel, dim3(8), dim3(256), 0, stream, x, ws);
  hipLaunchKernelGGL(rnn_persist, dim3(NB), dim3(NT),
                     8 * 2 * 512 * sizeof(float4) /* 128 KB dyn LDS */, stream,
                     x, lp_w, lp_b, lp_wout, lp_bout,
                     w_ih, b_ih, w_hh, b_hh, out, ws);
}